// Round 1
// baseline (353.919 us; speedup 1.0000x reference)
//
#include <hip/hip_runtime.h>
#include <hip/hip_bf16.h>
#include <stdint.h>

// SelfAttention: x(4,2048,1024) f32; W_qkv(3072,1024); W_out(1024,1024); b_out(1024)
// out = OutProj(Attn(QKV(x)))  f32 (4,2048,1024)
// Strategy: fp16 MFMA everywhere (threshold 5.5e-3 allows it; bf16 would not).

typedef _Float16 half8 __attribute__((ext_vector_type(8)));
typedef float floatx4 __attribute__((ext_vector_type(4)));

#define E 1024
#define NH 16
#define DH 64
#define SEQ 2048
#define BATCH 4

__device__ __forceinline__ void gload_lds16(const void* g, void* lds) {
  typedef __attribute__((address_space(1))) void gv;
  typedef __attribute__((address_space(3))) void lv;
  // dest = lds (wave-uniform) + lane*16; src is per-lane
  __builtin_amdgcn_global_load_lds((gv*)g, (lv*)lds, 16, 0, 0);
}

// ---------------------------------------------------------------- convert
__global__ __launch_bounds__(256) void cvt_f32_f16(const float* __restrict__ in,
                                                   _Float16* __restrict__ out, int n8) {
  int i = blockIdx.x * 256 + threadIdx.x;
  if (i >= n8) return;
  const float4* p = (const float4*)in;
  float4 a = p[2 * i], b = p[2 * i + 1];
  half8 h;
  h[0] = (_Float16)a.x; h[1] = (_Float16)a.y; h[2] = (_Float16)a.z; h[3] = (_Float16)a.w;
  h[4] = (_Float16)b.x; h[5] = (_Float16)b.y; h[6] = (_Float16)b.z; h[7] = (_Float16)b.w;
  ((half8*)out)[i] = h;
}

// ---------------------------------------------------------------- QKV GEMM
// C[8192,3072] = A[8192,1024] * W[3072,1024]^T ; scatter into q/k/v (b,h,tok,d) fp16
__global__ __launch_bounds__(256)
void gemm_qkv(const _Float16* __restrict__ A, const _Float16* __restrict__ W,
              _Float16* __restrict__ qo, _Float16* __restrict__ ko, _Float16* __restrict__ vo) {
  __shared__ __align__(16) _Float16 As[128 * 64];
  __shared__ __align__(16) _Float16 Bs[128 * 64];
  const int t = threadIdx.x;
  const int w = t >> 6, l = t & 63;
  const int wr = w >> 1, wc = w & 1;
  const int lr = l & 15, hi = l >> 4;
  const int tileRow = blockIdx.y * 128;
  const int tileCol = blockIdx.x * 128;
  const int ldsW = (t & ~63) * 16;
  floatx4 acc[4][4] = {};

  for (int k0 = 0; k0 < 1024; k0 += 64) {
    __syncthreads();
#pragma unroll
    for (int c = 0; c < 4; ++c) {
      int idx = c * 256 + t;
      int row = idx >> 3, g = idx & 7;
      gload_lds16(A + (size_t)(tileRow + row) * 1024 + k0 + g * 8, (char*)As + c * 4096 + ldsW);
      gload_lds16(W + (size_t)(tileCol + row) * 1024 + k0 + g * 8, (char*)Bs + c * 4096 + ldsW);
    }
    __syncthreads();
#pragma unroll
    for (int kk = 0; kk < 2; ++kk) {
      half8 af[4], bf[4];
#pragma unroll
      for (int m = 0; m < 4; ++m)
        af[m] = *(const half8*)(As + (wr * 64 + m * 16 + lr) * 64 + kk * 32 + hi * 8);
#pragma unroll
      for (int n = 0; n < 4; ++n)
        bf[n] = *(const half8*)(Bs + (wc * 64 + n * 16 + lr) * 64 + kk * 32 + hi * 8);
#pragma unroll
      for (int m = 0; m < 4; ++m)
#pragma unroll
        for (int n = 0; n < 4; ++n)
          acc[m][n] = __builtin_amdgcn_mfma_f32_16x16x32_f16(af[m], bf[n], acc[m][n], 0, 0, 0);
    }
  }
  // epilogue: C/D layout col=lane&15, row=(lane>>4)*4+j  [m89]
  const int sec = tileCol >> 10;  // 128-tile never straddles a 1024 section
  _Float16* dst = sec == 0 ? qo : (sec == 1 ? ko : vo);
  const int b = tileRow >> 11;
  const int tokBase = (tileRow & 2047) + wr * 64;
#pragma unroll
  for (int n = 0; n < 4; ++n) {
    int col = (tileCol & 1023) + wc * 64 + n * 16 + lr;
    int h = col >> 6, d = col & 63;
    _Float16* base = dst + (((size_t)b * NH + h) * SEQ + tokBase) * DH + d;
#pragma unroll
    for (int m = 0; m < 4; ++m)
#pragma unroll
      for (int j = 0; j < 4; ++j)
        base[(size_t)(m * 16 + hi * 4 + j) * DH] = (_Float16)acc[m][n][j];
  }
}

// ---------------------------------------------------------------- v -> vT
__global__ __launch_bounds__(256)
void transpose_v(const _Float16* __restrict__ V, _Float16* __restrict__ VT) {
  __shared__ __align__(16) _Float16 L[64][80];  // pad 80 (160B rows, 16B aligned)
  const int bh = blockIdx.y, tt = blockIdx.x;
  const int t = threadIdx.x;
  const _Float16* vb = V + ((size_t)bh * SEQ + tt * 64) * DH;
#pragma unroll
  for (int c = 0; c < 2; ++c) {
    int idx = c * 256 + t;
    int row = idx >> 3, d0 = (idx & 7) * 8;
    *(half8*)&L[row][d0] = *(const half8*)(vb + row * DH + d0);
  }
  __syncthreads();
  _Float16* ob = VT + (size_t)bh * DH * SEQ + tt * 64;
#pragma unroll
  for (int c = 0; c < 2; ++c) {
    int idx = c * 256 + t;
    int d = idx >> 3, k0 = (idx & 7) * 8;
    half8 x;
#pragma unroll
    for (int jj = 0; jj < 8; ++jj) x[jj] = L[k0 + jj][d];
    *(half8*)(ob + (size_t)d * SEQ + k0) = x;
  }
}

// ---------------------------------------------------------------- flash attention
// grid(32 qtiles, 64 bh); 4 waves x 16 q-rows; KV tile 64; K/V/P LDS XOR-swizzled
__global__ __launch_bounds__(256)
void attn(const _Float16* __restrict__ Q, const _Float16* __restrict__ Kg,
          const _Float16* __restrict__ VT, _Float16* __restrict__ O) {
  __shared__ __align__(16) _Float16 Ks[64 * 64];       // [key][d]
  __shared__ __align__(16) _Float16 Vs[64 * 64];       // [d][key] (from vT)
  __shared__ __align__(16) _Float16 Ps[4][16 * 64];    // per-wave P [q][key]
  const int bh = blockIdx.y, qt = blockIdx.x;
  const int t = threadIdx.x, w = t >> 6, l = t & 63;
  const int lr = l & 15, hi = l >> 4;
  const int ldsW = (t & ~63) * 16;
  const _Float16* qb = Q + ((size_t)bh * SEQ + qt * 64 + w * 16) * DH;
  half8 qf[2];
  qf[0] = *(const half8*)(qb + lr * DH + hi * 8);
  qf[1] = *(const half8*)(qb + lr * DH + 32 + hi * 8);
  floatx4 o_acc[4] = {};
  float m_run[4], l_run[4];
#pragma unroll
  for (int j = 0; j < 4; ++j) { m_run[j] = -1e30f; l_run[j] = 0.f; }
  const float sc = 0.125f * 1.44269504088896f;  // 1/sqrt(64) * log2(e)
  const _Float16* kb = Kg + (size_t)bh * SEQ * DH;
  const _Float16* vb = VT + (size_t)bh * DH * SEQ;
  _Float16* pw = &Ps[w][0];

  for (int kt = 0; kt < SEQ / 64; ++kt) {
    __syncthreads();
    // stage K [64][64] and V^T [64][64]; linear LDS dest, inverse-swizzled source
#pragma unroll
    for (int c = 0; c < 2; ++c) {
      int idx = c * 256 + t;
      int row = idx >> 3, g = idx & 7, gs = g ^ (row & 7);
      gload_lds16(kb + (size_t)(kt * 64 + row) * DH + gs * 8, (char*)Ks + c * 4096 + ldsW);
      gload_lds16(vb + (size_t)row * SEQ + kt * 64 + gs * 8, (char*)Vs + c * 4096 + ldsW);
    }
    __syncthreads();
    // S = Q K^T : D col = key, row = q
    floatx4 s[4] = {};
#pragma unroll
    for (int kk = 0; kk < 2; ++kk) {
      int gl = kk * 4 + hi;
#pragma unroll
      for (int n = 0; n < 4; ++n) {
        int key = n * 16 + lr;
        half8 bf = *(const half8*)((char*)Ks + key * 128 + ((gl ^ (key & 7)) << 4));
        s[n] = __builtin_amdgcn_mfma_f32_16x16x32_f16(qf[kk], bf, s[n], 0, 0, 0);
      }
    }
    // online softmax (rows j; reduce over 16 lanes sharing hi)
    float p[4][4];
#pragma unroll
    for (int j = 0; j < 4; ++j) {
      float sv0 = s[0][j] * sc, sv1 = s[1][j] * sc, sv2 = s[2][j] * sc, sv3 = s[3][j] * sc;
      float mx = fmaxf(fmaxf(sv0, sv1), fmaxf(sv2, sv3));
#pragma unroll
      for (int off = 1; off <= 8; off <<= 1) mx = fmaxf(mx, __shfl_xor(mx, off));
      float mn = fmaxf(m_run[j], mx);
      float fac = exp2f(m_run[j] - mn);
      m_run[j] = mn;
      float p0 = exp2f(sv0 - mn), p1 = exp2f(sv1 - mn);
      float p2 = exp2f(sv2 - mn), p3 = exp2f(sv3 - mn);
      p[0][j] = p0; p[1][j] = p1; p[2][j] = p2; p[3][j] = p3;
      float rs = p0 + p1 + p2 + p3;
#pragma unroll
      for (int off = 1; off <= 8; off <<= 1) rs += __shfl_xor(rs, off);
      l_run[j] = l_run[j] * fac + rs;
#pragma unroll
      for (int n = 0; n < 4; ++n) o_acc[n][j] *= fac;
    }
    // P -> per-wave LDS (swizzled), re-read as MFMA A fragments
#pragma unroll
    for (int n = 0; n < 4; ++n) {
      int colk = n * 16 + lr;
#pragma unroll
      for (int j = 0; j < 4; ++j) {
        int row = hi * 4 + j;
        *(_Float16*)((char*)pw + row * 128 + (((colk >> 3) ^ (row & 7)) << 4) +
                     ((colk & 7) << 1)) = (_Float16)p[n][j];
      }
    }
    half8 pf[2];
#pragma unroll
    for (int kk = 0; kk < 2; ++kk) {
      int gl = kk * 4 + hi;
      pf[kk] = *(const half8*)((char*)pw + lr * 128 + ((gl ^ (lr & 7)) << 4));
    }
    // O += P V
#pragma unroll
    for (int kk = 0; kk < 2; ++kk) {
      int gl = kk * 4 + hi;
#pragma unroll
      for (int n = 0; n < 4; ++n) {
        int d = n * 16 + lr;
        half8 vf = *(const half8*)((char*)Vs + d * 128 + ((gl ^ (d & 7)) << 4));
        o_acc[n] = __builtin_amdgcn_mfma_f32_16x16x32_f16(pf[kk], vf, o_acc[n], 0, 0, 0);
      }
    }
  }
  const int b = bh >> 4, h = bh & 15;
#pragma unroll
  for (int j = 0; j < 4; ++j) {
    float inv = 1.f / l_run[j];
    int tok = qt * 64 + w * 16 + hi * 4 + j;
    _Float16* ob = O + ((size_t)b * SEQ + tok) * E + h * DH;
#pragma unroll
    for (int n = 0; n < 4; ++n) ob[n * 16 + lr] = (_Float16)(o_acc[n][j] * inv);
  }
}

// ---------------------------------------------------------------- out projection
__global__ __launch_bounds__(256)
void gemm_out(const _Float16* __restrict__ A, const _Float16* __restrict__ W,
              const float* __restrict__ bias, float* __restrict__ out) {
  __shared__ __align__(16) _Float16 As[128 * 64];
  __shared__ __align__(16) _Float16 Bs[128 * 64];
  const int t = threadIdx.x;
  const int w = t >> 6, l = t & 63;
  const int wr = w >> 1, wc = w & 1;
  const int lr = l & 15, hi = l >> 4;
  const int tileRow = blockIdx.y * 128;
  const int tileCol = blockIdx.x * 128;
  const int ldsW = (t & ~63) * 16;
  floatx4 acc[4][4] = {};

  for (int k0 = 0; k0 < 1024; k0 += 64) {
    __syncthreads();
#pragma unroll
    for (int c = 0; c < 4; ++c) {
      int idx = c * 256 + t;
      int row = idx >> 3, g = idx & 7;
      gload_lds16(A + (size_t)(tileRow + row) * 1024 + k0 + g * 8, (char*)As + c * 4096 + ldsW);
      gload_lds16(W + (size_t)(tileCol + row) * 1024 + k0 + g * 8, (char*)Bs + c * 4096 + ldsW);
    }
    __syncthreads();
#pragma unroll
    for (int kk = 0; kk < 2; ++kk) {
      half8 af[4], bf[4];
#pragma unroll
      for (int m = 0; m < 4; ++m)
        af[m] = *(const half8*)(As + (wr * 64 + m * 16 + lr) * 64 + kk * 32 + hi * 8);
#pragma unroll
      for (int n = 0; n < 4; ++n)
        bf[n] = *(const half8*)(Bs + (wc * 64 + n * 16 + lr) * 64 + kk * 32 + hi * 8);
#pragma unroll
      for (int m = 0; m < 4; ++m)
#pragma unroll
        for (int n = 0; n < 4; ++n)
          acc[m][n] = __builtin_amdgcn_mfma_f32_16x16x32_f16(af[m], bf[n], acc[m][n], 0, 0, 0);
    }
  }
#pragma unroll
  for (int n = 0; n < 4; ++n) {
    int col = tileCol + wc * 64 + n * 16 + lr;
    float bv = bias[col];
#pragma unroll
    for (int m = 0; m < 4; ++m) {
      int row = tileRow + wr * 64 + m * 16 + hi * 4;
#pragma unroll
      for (int j = 0; j < 4; ++j)
        out[(size_t)(row + j) * E + col] = acc[m][n][j] + bv;
    }
  }
}

// ---------------------------------------------------------------- launch
extern "C" void kernel_launch(void* const* d_in, const int* in_sizes, int n_in,
                              void* d_out, int out_size, void* d_ws, size_t ws_size,
                              hipStream_t stream) {
  const float* x = (const float*)d_in[0];
  const float* Wqkv = (const float*)d_in[1];
  const float* Wout = (const float*)d_in[2];
  const float* bout = (const float*)d_in[3];
  float* out = (float*)d_out;
  char* ws = (char*)d_ws;
  // workspace layout (72 MB):
  //   [0,16M)   x16, later reused as vT
  //   [16,32M)  q16   [32,48M) k16   [48,64M) v16, later reused as attn-out fp16
  //   [64,70M)  Wqkv16   [70,72M) Wout16
  _Float16* x16 = (_Float16*)(ws);
  _Float16* q16 = (_Float16*)(ws + (16u << 20));
  _Float16* k16 = (_Float16*)(ws + (32u << 20));
  _Float16* v16 = (_Float16*)(ws + (48u << 20));
  _Float16* wq16 = (_Float16*)(ws + (64u << 20));
  _Float16* wo16 = (_Float16*)(ws + (70u << 20));
  _Float16* vt16 = x16;  // x dead after gemm_qkv
  _Float16* ao16 = v16;  // v dead after transpose_v

  int n8x = in_sizes[0] / 8, n8q = in_sizes[1] / 8, n8o = in_sizes[2] / 8;
  cvt_f32_f16<<<(n8x + 255) / 256, 256, 0, stream>>>(x, x16, n8x);
  cvt_f32_f16<<<(n8q + 255) / 256, 256, 0, stream>>>(Wqkv, wq16, n8q);
  cvt_f32_f16<<<(n8o + 255) / 256, 256, 0, stream>>>(Wout, wo16, n8o);
  gemm_qkv<<<dim3(24, 64), 256, 0, stream>>>(x16, wq16, q16, k16, v16);
  transpose_v<<<dim3(32, 64), 256, 0, stream>>>(v16, vt16);
  attn<<<dim3(32, 64), 256, 0, stream>>>(q16, k16, vt16, ao16);
  gemm_out<<<dim3(8, 64), 256, 0, stream>>>(ao16, wo16, bout, out);
}

// Round 3
// 260.194 us; speedup vs baseline: 1.3602x; 1.3602x over previous
//
#include <hip/hip_runtime.h>
#include <hip/hip_bf16.h>
#include <stdint.h>

// SelfAttention: x(4,2048,1024) f32; W_qkv(3072,1024); W_out(1024,1024); b_out(1024)
// out = OutProj(Attn(QKV(x)))  f32 (4,2048,1024)
// Strategy: fp16 MFMA everywhere (threshold 5.5e-3; measured absmax ~1e-3).
// R3: R2's swapped-QK^T attention with the cvt_pkrtz type fixed (__fp16 vector).

typedef _Float16 half8 __attribute__((ext_vector_type(8)));
typedef __fp16 fp16x2 __attribute__((ext_vector_type(2)));  // native cvt_pkrtz type
typedef float floatx4 __attribute__((ext_vector_type(4)));

#define E 1024
#define NH 16
#define DH 64
#define SEQ 2048
#define BATCH 4

__device__ __forceinline__ void gload_lds16(const void* g, void* lds) {
  typedef __attribute__((address_space(1))) void gv;
  typedef __attribute__((address_space(3))) void lv;
  __builtin_amdgcn_global_load_lds((gv*)g, (lv*)lds, 16, 0, 0);
}

__device__ __forceinline__ float fast_exp2(float x) {
#if __has_builtin(__builtin_amdgcn_exp2f)
  return __builtin_amdgcn_exp2f(x);
#else
  return exp2f(x);
#endif
}

// ---------------------------------------------------------------- convert
__global__ __launch_bounds__(256) void cvt_f32_f16(const float* __restrict__ in,
                                                   _Float16* __restrict__ out, int n8) {
  int i = blockIdx.x * 256 + threadIdx.x;
  if (i >= n8) return;
  const float4* p = (const float4*)in;
  float4 a = p[2 * i], b = p[2 * i + 1];
  half8 h;
  h[0] = (_Float16)a.x; h[1] = (_Float16)a.y; h[2] = (_Float16)a.z; h[3] = (_Float16)a.w;
  h[4] = (_Float16)b.x; h[5] = (_Float16)b.y; h[6] = (_Float16)b.z; h[7] = (_Float16)b.w;
  ((half8*)out)[i] = h;
}

// ---------------------------------------------------------------- QKV GEMM
// C[8192,3072] = A[8192,1024] * W[3072,1024]^T ; scatter into q/k/v (b,h,tok,d) fp16
// Q gets pre-scaled by 1/sqrt(Dh) * log2(e) so attention softmax can use exp2 directly.
__global__ __launch_bounds__(256)
void gemm_qkv(const _Float16* __restrict__ A, const _Float16* __restrict__ W,
              _Float16* __restrict__ qo, _Float16* __restrict__ ko, _Float16* __restrict__ vo) {
  __shared__ __align__(16) _Float16 As[128 * 64];
  __shared__ __align__(16) _Float16 Bs[128 * 64];
  const int t = threadIdx.x;
  const int w = t >> 6, l = t & 63;
  const int wr = w >> 1, wc = w & 1;
  const int lr = l & 15, hi = l >> 4;
  const int tileRow = blockIdx.y * 128;
  const int tileCol = blockIdx.x * 128;
  const int ldsW = (t & ~63) * 16;
  floatx4 acc[4][4] = {};

  for (int k0 = 0; k0 < 1024; k0 += 64) {
    __syncthreads();
#pragma unroll
    for (int c = 0; c < 4; ++c) {
      int idx = c * 256 + t;
      int row = idx >> 3, g = idx & 7;
      gload_lds16(A + (size_t)(tileRow + row) * 1024 + k0 + g * 8, (char*)As + c * 4096 + ldsW);
      gload_lds16(W + (size_t)(tileCol + row) * 1024 + k0 + g * 8, (char*)Bs + c * 4096 + ldsW);
    }
    __syncthreads();
#pragma unroll
    for (int kk = 0; kk < 2; ++kk) {
      half8 af[4], bf[4];
#pragma unroll
      for (int m = 0; m < 4; ++m)
        af[m] = *(const half8*)(As + (wr * 64 + m * 16 + lr) * 64 + kk * 32 + hi * 8);
#pragma unroll
      for (int n = 0; n < 4; ++n)
        bf[n] = *(const half8*)(Bs + (wc * 64 + n * 16 + lr) * 64 + kk * 32 + hi * 8);
#pragma unroll
      for (int m = 0; m < 4; ++m)
#pragma unroll
        for (int n = 0; n < 4; ++n)
          acc[m][n] = __builtin_amdgcn_mfma_f32_16x16x32_f16(af[m], bf[n], acc[m][n], 0, 0, 0);
    }
  }
  // epilogue: C/D layout col=lane&15, row=(lane>>4)*4+j  [m89]
  const int sec = tileCol >> 10;  // 128-tile never straddles a 1024 section
  _Float16* dst = sec == 0 ? qo : (sec == 1 ? ko : vo);
  const float scaleq = sec == 0 ? 0.18033688011112042f : 1.0f;  // 0.125 * log2(e)
  const int b = tileRow >> 11;
  const int tokBase = (tileRow & 2047) + wr * 64;
#pragma unroll
  for (int n = 0; n < 4; ++n) {
    int col = (tileCol & 1023) + wc * 64 + n * 16 + lr;
    int h = col >> 6, d = col & 63;
    _Float16* base = dst + (((size_t)b * NH + h) * SEQ + tokBase) * DH + d;
#pragma unroll
    for (int m = 0; m < 4; ++m)
#pragma unroll
      for (int j = 0; j < 4; ++j)
        base[(size_t)(m * 16 + hi * 4 + j) * DH] = (_Float16)(acc[m][n][j] * scaleq);
  }
}

// ---------------------------------------------------------------- v -> vT
__global__ __launch_bounds__(256)
void transpose_v(const _Float16* __restrict__ V, _Float16* __restrict__ VT) {
  __shared__ __align__(16) _Float16 L[64][80];
  const int bh = blockIdx.y, tt = blockIdx.x;
  const int t = threadIdx.x;
  const _Float16* vb = V + ((size_t)bh * SEQ + tt * 64) * DH;
#pragma unroll
  for (int c = 0; c < 2; ++c) {
    int idx = c * 256 + t;
    int row = idx >> 3, d0 = (idx & 7) * 8;
    *(half8*)&L[row][d0] = *(const half8*)(vb + row * DH + d0);
  }
  __syncthreads();
  _Float16* ob = VT + (size_t)bh * DH * SEQ + tt * 64;
#pragma unroll
  for (int c = 0; c < 2; ++c) {
    int idx = c * 256 + t;
    int d = idx >> 3, k0 = (idx & 7) * 8;
    half8 x;
#pragma unroll
    for (int jj = 0; jj < 8; ++jj) x[jj] = L[k0 + jj][d];
    *(half8*)(ob + (size_t)d * SEQ + k0) = x;
  }
}

// ---------------------------------------------------------------- flash attention
// grid(32 qtiles, 64 bh); 4 waves x 16 q-rows; KV tile 64.
// Swapped QK^T: S^T = mfma(A=K, B=Q) -> lane holds 16 keys of ONE q-row (q=lr).
// Softmax lane-local (2 shfl per reduce); P packed via cvt_pkrtz -> 4 ds_write_b64
// into per-wave [16 q][64 key] buffer (XOR-swizzled 16B units), re-read as A-frags.
__global__ __launch_bounds__(256)
void attn(const _Float16* __restrict__ Q, const _Float16* __restrict__ Kg,
          const _Float16* __restrict__ VT, _Float16* __restrict__ O) {
  __shared__ __align__(16) _Float16 Ks[64 * 64];     // [key][d] swizzled
  __shared__ __align__(16) _Float16 Vs[64 * 64];     // [d][key] swizzled
  __shared__ __align__(16) _Float16 Ps[4][16 * 64];  // per-wave P [q][key] swizzled
  const int bh = blockIdx.y, qt = blockIdx.x;
  const int t = threadIdx.x, w = t >> 6, l = t & 63;
  const int lr = l & 15, hi = l >> 4;
  const int ldsW = (t & ~63) * 16;
  // Q as B-frag: lane holds Q[q=lr][k = kk*32 + hi*8 + 0..7] (pre-scaled)
  const _Float16* qb = Q + ((size_t)bh * SEQ + qt * 64 + w * 16) * DH;
  half8 qf[2];
  qf[0] = *(const half8*)(qb + lr * DH + hi * 8);
  qf[1] = *(const half8*)(qb + lr * DH + 32 + hi * 8);
  floatx4 o_acc[4] = {};
  float m_run = -1e30f, l_run = 0.f;
  const _Float16* kb = Kg + (size_t)bh * SEQ * DH;
  const _Float16* vb = VT + (size_t)bh * DH * SEQ;
  char* pw = (char*)&Ps[w][0];
  const int lrm = lr & 7;
  // P-LDS addresses (loop-invariant): row q=lr (128B), 16B units XOR-swizzled by lr&7
  uint32_t wra[4], rda[2];
#pragma unroll
  for (int n = 0; n < 4; ++n)
    wra[n] = lr * 128 + ((((2 * n + (hi >> 1)) ^ lrm)) << 4) + (hi & 1) * 8;
#pragma unroll
  for (int kk = 0; kk < 2; ++kk)
    rda[kk] = lr * 128 + (((4 * kk + hi) ^ lrm) << 4);

  for (int kt = 0; kt < SEQ / 64; ++kt) {
    __syncthreads();
#pragma unroll
    for (int c = 0; c < 2; ++c) {
      int idx = c * 256 + t;
      int row = idx >> 3, g = idx & 7, gs = g ^ (row & 7);
      gload_lds16(kb + (size_t)(kt * 64 + row) * DH + gs * 8, (char*)Ks + c * 4096 + ldsW);
      gload_lds16(vb + (size_t)row * SEQ + kt * 64 + gs * 8, (char*)Vs + c * 4096 + ldsW);
    }
    __syncthreads();
    // S^T: s[n][j] = S[key = 16n + 4hi + j][q = lr]
    floatx4 s[4] = {};
#pragma unroll
    for (int kk = 0; kk < 2; ++kk) {
      int gl = kk * 4 + hi;
#pragma unroll
      for (int n = 0; n < 4; ++n) {
        int key = n * 16 + lr;
        half8 af = *(const half8*)((char*)Ks + key * 128 + ((gl ^ (key & 7)) << 4));
        s[n] = __builtin_amdgcn_mfma_f32_16x16x32_f16(af, qf[kk], s[n], 0, 0, 0);
      }
    }
    // row max: in-lane 16 + xor16/32 (4 lanes share q-row lr)
    float m01 = fmaxf(fmaxf(s[0][0], s[0][1]), fmaxf(s[0][2], s[0][3]));
    float m23 = fmaxf(fmaxf(s[1][0], s[1][1]), fmaxf(s[1][2], s[1][3]));
    float m45 = fmaxf(fmaxf(s[2][0], s[2][1]), fmaxf(s[2][2], s[2][3]));
    float m67 = fmaxf(fmaxf(s[3][0], s[3][1]), fmaxf(s[3][2], s[3][3]));
    float mx = fmaxf(fmaxf(m01, m23), fmaxf(m45, m67));
    mx = fmaxf(mx, __shfl_xor(mx, 16));
    mx = fmaxf(mx, __shfl_xor(mx, 32));
    // defer-max: rescale only when tile max exceeds running max by >10 (log2 units)
    if (__any(mx > m_run + 10.f)) {
      float mn = fmaxf(m_run, mx);
      float fac = fast_exp2(m_run - mn);
      m_run = mn;
      l_run *= fac;
#pragma unroll
      for (int j = 0; j < 4; ++j) {
        float fj = __shfl(fac, hi * 4 + j);  // fac for q-row 4hi+j lives at lane 4hi+j
#pragma unroll
        for (int n = 0; n < 4; ++n) o_acc[n][j] *= fj;
      }
    }
    // p = exp2(s - m); pack pairs (key-consecutive); row-sum
    fp16x2 pk[4][2];
    float rs = 0.f;
#pragma unroll
    for (int n = 0; n < 4; ++n) {
      float p0 = fast_exp2(s[n][0] - m_run);
      float p1 = fast_exp2(s[n][1] - m_run);
      float p2 = fast_exp2(s[n][2] - m_run);
      float p3 = fast_exp2(s[n][3] - m_run);
      pk[n][0] = __builtin_amdgcn_cvt_pkrtz(p0, p1);
      pk[n][1] = __builtin_amdgcn_cvt_pkrtz(p2, p3);
      rs += p0 + p1 + p2 + p3;
    }
    rs += __shfl_xor(rs, 16);
    rs += __shfl_xor(rs, 32);
    l_run += rs;
    // P -> per-wave LDS: 4x ds_write_b64 (keys 16n+4hi+0..3 at row q=lr)
#pragma unroll
    for (int n = 0; n < 4; ++n) {
      uint2 v;
      v.x = __builtin_bit_cast(uint32_t, pk[n][0]);
      v.y = __builtin_bit_cast(uint32_t, pk[n][1]);
      *(uint2*)(pw + wra[n]) = v;
    }
    // A-frags: P[q=lr][key = kk*32 + hi*8 + 0..7]
    half8 pf[2];
    pf[0] = *(const half8*)(pw + rda[0]);
    pf[1] = *(const half8*)(pw + rda[1]);
    // O += P V
#pragma unroll
    for (int kk = 0; kk < 2; ++kk) {
      int gl = kk * 4 + hi;
#pragma unroll
      for (int n = 0; n < 4; ++n) {
        int d = n * 16 + lr;
        half8 vf = *(const half8*)((char*)Vs + d * 128 + ((gl ^ (d & 7)) << 4));
        o_acc[n] = __builtin_amdgcn_mfma_f32_16x16x32_f16(pf[kk], vf, o_acc[n], 0, 0, 0);
      }
    }
  }
  // epilogue: o_acc[n][j] = O[q = 4hi+j][d = 16n+lr]; l_run lives at lane q (=lr)
  const int b = bh >> 4, h = bh & 15;
#pragma unroll
  for (int j = 0; j < 4; ++j) {
    float lj = __shfl(l_run, hi * 4 + j);
    float inv = 1.f / lj;
    int tok = qt * 64 + w * 16 + hi * 4 + j;
    _Float16* ob = O + ((size_t)b * SEQ + tok) * E + h * DH;
#pragma unroll
    for (int n = 0; n < 4; ++n) ob[n * 16 + lr] = (_Float16)(o_acc[n][j] * inv);
  }
}

// ---------------------------------------------------------------- out projection
__global__ __launch_bounds__(256)
void gemm_out(const _Float16* __restrict__ A, const _Float16* __restrict__ W,
              const float* __restrict__ bias, float* __restrict__ out) {
  __shared__ __align__(16) _Float16 As[128 * 64];
  __shared__ __align__(16) _Float16 Bs[128 * 64];
  const int t = threadIdx.x;
  const int w = t >> 6, l = t & 63;
  const int wr = w >> 1, wc = w & 1;
  const int lr = l & 15, hi = l >> 4;
  const int tileRow = blockIdx.y * 128;
  const int tileCol = blockIdx.x * 128;
  const int ldsW = (t & ~63) * 16;
  floatx4 acc[4][4] = {};

  for (int k0 = 0; k0 < 1024; k0 += 64) {
    __syncthreads();
#pragma unroll
    for (int c = 0; c < 4; ++c) {
      int idx = c * 256 + t;
      int row = idx >> 3, g = idx & 7;
      gload_lds16(A + (size_t)(tileRow + row) * 1024 + k0 + g * 8, (char*)As + c * 4096 + ldsW);
      gload_lds16(W + (size_t)(tileCol + row) * 1024 + k0 + g * 8, (char*)Bs + c * 4096 + ldsW);
    }
    __syncthreads();
#pragma unroll
    for (int kk = 0; kk < 2; ++kk) {
      half8 af[4], bf[4];
#pragma unroll
      for (int m = 0; m < 4; ++m)
        af[m] = *(const half8*)(As + (wr * 64 + m * 16 + lr) * 64 + kk * 32 + hi * 8);
#pragma unroll
      for (int n = 0; n < 4; ++n)
        bf[n] = *(const half8*)(Bs + (wc * 64 + n * 16 + lr) * 64 + kk * 32 + hi * 8);
#pragma unroll
      for (int m = 0; m < 4; ++m)
#pragma unroll
        for (int n = 0; n < 4; ++n)
          acc[m][n] = __builtin_amdgcn_mfma_f32_16x16x32_f16(af[m], bf[n], acc[m][n], 0, 0, 0);
    }
  }
#pragma unroll
  for (int n = 0; n < 4; ++n) {
    int col = tileCol + wc * 64 + n * 16 + lr;
    float bv = bias[col];
#pragma unroll
    for (int m = 0; m < 4; ++m) {
      int row = tileRow + wr * 64 + m * 16 + hi * 4;
#pragma unroll
      for (int j = 0; j < 4; ++j)
        out[(size_t)(row + j) * E + col] = acc[m][n][j] + bv;
    }
  }
}

// ---------------------------------------------------------------- launch
extern "C" void kernel_launch(void* const* d_in, const int* in_sizes, int n_in,
                              void* d_out, int out_size, void* d_ws, size_t ws_size,
                              hipStream_t stream) {
  const float* x = (const float*)d_in[0];
  const float* Wqkv = (const float*)d_in[1];
  const float* Wout = (const float*)d_in[2];
  const float* bout = (const float*)d_in[3];
  float* out = (float*)d_out;
  char* ws = (char*)d_ws;
  _Float16* x16 = (_Float16*)(ws);
  _Float16* q16 = (_Float16*)(ws + (16u << 20));
  _Float16* k16 = (_Float16*)(ws + (32u << 20));
  _Float16* v16 = (_Float16*)(ws + (48u << 20));
  _Float16* wq16 = (_Float16*)(ws + (64u << 20));
  _Float16* wo16 = (_Float16*)(ws + (70u << 20));
  _Float16* vt16 = x16;  // x dead after gemm_qkv
  _Float16* ao16 = v16;  // v dead after transpose_v

  int n8x = in_sizes[0] / 8, n8q = in_sizes[1] / 8, n8o = in_sizes[2] / 8;
  cvt_f32_f16<<<(n8x + 255) / 256, 256, 0, stream>>>(x, x16, n8x);
  cvt_f32_f16<<<(n8q + 255) / 256, 256, 0, stream>>>(Wqkv, wq16, n8q);
  cvt_f32_f16<<<(n8o + 255) / 256, 256, 0, stream>>>(Wout, wo16, n8o);
  gemm_qkv<<<dim3(24, 64), 256, 0, stream>>>(x16, wq16, q16, k16, v16);
  transpose_v<<<dim3(32, 64), 256, 0, stream>>>(v16, vt16);
  attn<<<dim3(32, 64), 256, 0, stream>>>(q16, k16, vt16, ao16);
  gemm_out<<<dim3(8, 64), 256, 0, stream>>>(ao16, wo16, bout, out);
}